// Round 1
// baseline (3127.757 us; speedup 1.0000x reference)
//
#include <hip/hip_runtime.h>
#include <hip/hip_bf16.h>

#define SDIM 38
#define RDIM 340
#define HC   128
#define SC   4
#define RC   3
#define NO   7
#define LCONV 4
#define BATCH 512
#define SR   378
#define NN   (BATCH*SR)     // 193536
#define NS   (BATCH*SDIM)   // 19456
#define NR   (BATCH*RDIM)   // 174080
#define EE   3072000
#define EPSV 1e-5f
#define SCAN_NB 189         // NN/1024

__device__ __forceinline__ float leaky(float v){ return v > 0.f ? v : 0.2f*v; }

// ---------------- batchnorm stats ----------------
__global__ void stats_s_kernel(const float* __restrict__ s_x, float* __restrict__ stats){
    int tid = threadIdx.x;
    int r = blockIdx.x*256 + tid;
    float4 v = make_float4(0.f,0.f,0.f,0.f);
    if (r < NS) v = *(const float4*)(s_x + (size_t)r*SC);
    __shared__ float sh[256][8];
    sh[tid][0]=v.x; sh[tid][1]=v.y; sh[tid][2]=v.z; sh[tid][3]=v.w;
    sh[tid][4]=v.x*v.x; sh[tid][5]=v.y*v.y; sh[tid][6]=v.z*v.z; sh[tid][7]=v.w*v.w;
    __syncthreads();
    for (int s=128; s>0; s>>=1){
        if (tid < s){
            #pragma unroll
            for (int k=0;k<8;k++) sh[tid][k]+=sh[tid+s][k];
        }
        __syncthreads();
    }
    if (tid < 8) atomicAdd(&stats[tid], sh[0][tid]);
}

__global__ void stats_r_kernel(const float* __restrict__ r_x, float* __restrict__ stats){
    int tid = threadIdx.x;
    int r = blockIdx.x*256 + tid;
    float4 v = make_float4(0.f,0.f,0.f,0.f);
    if (r < NR) v = *(const float4*)(r_x + (size_t)r*8);
    __shared__ float sh[256][8];
    sh[tid][0]=v.x; sh[tid][1]=v.y; sh[tid][2]=v.z;
    sh[tid][3]=v.x*v.x; sh[tid][4]=v.y*v.y; sh[tid][5]=v.z*v.z;
    sh[tid][6]=0.f; sh[tid][7]=0.f;
    __syncthreads();
    for (int s=128; s>0; s>>=1){
        if (tid < s){
            #pragma unroll
            for (int k=0;k<6;k++) sh[tid][k]+=sh[tid+s][k];
        }
        __syncthreads();
    }
    if (tid < 6) atomicAdd(&stats[8+tid], sh[0][tid]);
}

__global__ void finalize_stats_kernel(float* __restrict__ st,
        const float* __restrict__ bn_s_w, const float* __restrict__ bn_s_b,
        const float* __restrict__ bn_r_w, const float* __restrict__ bn_r_b){
    int t = threadIdx.x;
    if (t < SC){
        float m  = st[t] * (1.f/NS);
        float var= st[4+t] * (1.f/NS) - m*m;
        float sc = rsqrtf(var + EPSV) * bn_s_w[t];
        st[16+t] = sc; st[20+t] = bn_s_b[t] - m*sc;
    } else if (t >= 8 && t < 8+RC){
        int k = t-8;
        float m  = st[8+k] * (1.f/NR);
        float var= st[11+k] * (1.f/NR) - m*m;
        float sc = rsqrtf(var + EPSV) * bn_r_w[k];
        st[24+k] = sc; st[27+k] = bn_r_b[k] - m*sc;
    }
}

// ---------------- node features ----------------
__global__ void feature_kernel(const float* __restrict__ s_x, const float* __restrict__ r_x,
        const float* __restrict__ stats, const float* __restrict__ lin_s_w,
        const float* __restrict__ lin_r_w, float* __restrict__ x){
    int node = blockIdx.x*2 + (threadIdx.x >> 7);
    int c = threadIdx.x & 127;
    int b = node / SR;
    int p = node - b*SR;
    float acc;
    if (p < SDIM){
        int row = b*SDIM + p;
        float4 v = *(const float4*)(s_x + (size_t)row*SC);
        float i0 = v.x*stats[16]+stats[20];
        float i1 = v.y*stats[17]+stats[21];
        float i2 = v.z*stats[18]+stats[22];
        float i3 = v.w*stats[19]+stats[23];
        acc = i0*lin_s_w[0*HC+c] + i1*lin_s_w[1*HC+c] + i2*lin_s_w[2*HC+c] + i3*lin_s_w[3*HC+c];
    } else {
        int row = b*RDIM + (p - SDIM);
        float4 v = *(const float4*)(r_x + (size_t)row*8);
        float i0 = v.x*stats[24]+stats[27];
        float i1 = v.y*stats[25]+stats[28];
        float i2 = v.z*stats[26]+stats[29];
        acc = i0*lin_r_w[0*HC+c] + i1*lin_r_w[1*HC+c] + i2*lin_r_w[2*HC+c];
    }
    x[(size_t)node*HC + c] = leaky(acc);
}

// ---------------- degree / CSR build ----------------
__global__ void count_kernel(const int* __restrict__ dst, int* __restrict__ cnt){
    int e = blockIdx.x*256 + threadIdx.x;
    atomicAdd(&cnt[dst[e]], 1);
}

__global__ void scan_block_kernel(const int* __restrict__ cnt, int* __restrict__ rp,
                                  int* __restrict__ bsum){
    __shared__ int sh[1024];
    int tid = threadIdx.x;
    int i = blockIdx.x*1024 + tid;
    int v = cnt[i];
    sh[tid] = v;
    __syncthreads();
    for (int off=1; off<1024; off<<=1){
        int t = (tid >= off) ? sh[tid-off] : 0;
        __syncthreads();
        sh[tid] += t;
        __syncthreads();
    }
    rp[i] = sh[tid] - v;                 // exclusive within block
    if (tid == 1023) bsum[blockIdx.x] = sh[1023];
}

__global__ void scan_sums_kernel(int* __restrict__ bsum, int* __restrict__ rp){
    int run = 0;
    for (int b=0;b<SCAN_NB;b++){ int t = bsum[b]; bsum[b] = run; run += t; }
    rp[NN] = run;
}

__global__ void offsets_kernel(int* __restrict__ rp, const int* __restrict__ bsum,
        const int* __restrict__ cnt, int* __restrict__ cursor, float* __restrict__ dinv){
    int i = blockIdx.x*256 + threadIdx.x;   // grid = NN/256 exact
    int r = rp[i] + bsum[i >> 10];
    rp[i] = r; cursor[i] = r;
    dinv[i] = rsqrtf((float)(cnt[i] + 1));  // +1 self loop
}

__global__ void scatter_kernel(const int* __restrict__ src, const int* __restrict__ dst,
        const float* __restrict__ dinv, int* __restrict__ cursor, int2* __restrict__ csr){
    int e = blockIdx.x*256 + threadIdx.x;
    int s = src[e], d = dst[e];
    int pos = atomicAdd(&cursor[d], 1);
    csr[pos] = make_int2(s, __float_as_int(dinv[s]*dinv[d]));
}

// ---------------- conv GEMM: xw = x @ W  (fp32, LDS-tiled) ----------------
__global__ __launch_bounds__(256) void gemm_kernel(const float* __restrict__ x,
        const float* __restrict__ Wg, float* __restrict__ xw){
    __shared__ float Ws[128*64];      // [k][c] pitch 64, 32 KB
    __shared__ float xs[64*66];       // [r][k-half] pitch 66, 16.9 KB
    int tid = threadIdx.x;
    int rowbase = blockIdx.x * 64;
    int colbase = blockIdx.y * 64;
    // stage W half (128 x 64)
    for (int idx = tid; idx < 128*64; idx += 256){
        int k = idx >> 6, c = idx & 63;
        Ws[idx] = Wg[k*HC + colbase + c];
    }
    int cg = tid & 15, rg = tid >> 4;
    int c0 = cg*4, r0 = rg*4;
    float acc[4][4];
    #pragma unroll
    for (int i=0;i<4;i++){ acc[i][0]=0.f; acc[i][1]=0.f; acc[i][2]=0.f; acc[i][3]=0.f; }
    for (int kk = 0; kk < 128; kk += 64){
        __syncthreads();
        for (int idx = tid; idx < 64*64; idx += 256){
            int r = idx >> 6, k = idx & 63;
            xs[r*66 + k] = x[(size_t)(rowbase + r)*HC + kk + k];
        }
        __syncthreads();
        #pragma unroll 8
        for (int k = 0; k < 64; k++){
            float4 w4 = *(const float4*)&Ws[(kk + k)*64 + c0];
            float x0 = xs[(r0+0)*66 + k];
            float x1 = xs[(r0+1)*66 + k];
            float x2 = xs[(r0+2)*66 + k];
            float x3 = xs[(r0+3)*66 + k];
            acc[0][0]+=x0*w4.x; acc[0][1]+=x0*w4.y; acc[0][2]+=x0*w4.z; acc[0][3]+=x0*w4.w;
            acc[1][0]+=x1*w4.x; acc[1][1]+=x1*w4.y; acc[1][2]+=x1*w4.z; acc[1][3]+=x1*w4.w;
            acc[2][0]+=x2*w4.x; acc[2][1]+=x2*w4.y; acc[2][2]+=x2*w4.z; acc[2][3]+=x2*w4.w;
            acc[3][0]+=x3*w4.x; acc[3][1]+=x3*w4.y; acc[3][2]+=x3*w4.z; acc[3][3]+=x3*w4.w;
        }
    }
    #pragma unroll
    for (int i=0;i<4;i++){
        float4 o = make_float4(acc[i][0], acc[i][1], acc[i][2], acc[i][3]);
        *(float4*)&xw[(size_t)(rowbase + r0 + i)*HC + colbase + c0] = o;
    }
}

// ---------------- aggregation: x += leaky(A_norm @ xw + b) ----------------
__global__ void agg_kernel(const float* __restrict__ xw, const int* __restrict__ rp,
        const int2* __restrict__ csr, const float* __restrict__ dinv,
        const float* __restrict__ bias, float* __restrict__ x){
    int node = blockIdx.x*2 + (threadIdx.x >> 7);
    int c = threadIdx.x & 127;
    float dn = dinv[node];
    float acc = dn*dn * xw[(size_t)node*HC + c];     // self loop
    int beg = rp[node], end = rp[node+1];
    for (int j = beg; j < end; j++){
        int2 e = csr[j];
        acc += __int_as_float(e.y) * xw[(size_t)e.x*HC + c];
    }
    size_t idx = (size_t)node*HC + c;
    x[idx] = x[idx] + leaky(acc + bias[c]);
}

// ---------------- channel-mean pool ----------------
__global__ void pool_kernel(const float* __restrict__ x, float* __restrict__ pooled){
    int wid = threadIdx.x >> 6;
    int lane = threadIdx.x & 63;
    int node = blockIdx.x*4 + wid;
    const float* row = x + (size_t)node*HC;
    float v = row[lane] + row[64 + lane];
    #pragma unroll
    for (int off=32; off>0; off>>=1) v += __shfl_down(v, off, 64);
    if (lane == 0) pooled[node] = v * (1.f/128.f);
}

// ---------------- heads: z, o, output ----------------
__global__ void head_kernel(const float* __restrict__ pooled, const float* __restrict__ r_x,
        const float* __restrict__ linr_w, const float* __restrict__ linr_b,
        const float* __restrict__ lino_w1, const float* __restrict__ lino_b1,
        const float* __restrict__ lino_w2, const float* __restrict__ lino_b2,
        float* __restrict__ out){
    int b = blockIdx.x, tid = threadIdx.x;
    __shared__ float red[128][8];
    __shared__ float hsh[128];
    __shared__ float zsh[8];
    float part[NO];
    #pragma unroll
    for (int j=0;j<NO;j++) part[j]=0.f;
    for (int i = tid; i < SR; i += 128){
        float pv = pooled[(size_t)b*SR + i];
        #pragma unroll
        for (int j=0;j<NO;j++) part[j] += pv * linr_w[i*NO + j];
    }
    #pragma unroll
    for (int j=0;j<NO;j++) red[tid][j] = part[j];
    // o path: h[c]
    const float* ox = r_x + (size_t)b*RDIM*8 + RC;
    float hv = lino_b1[tid];
    #pragma unroll
    for (int k=0;k<5;k++) hv += ox[k]*lino_w1[k*HC + tid];
    hsh[tid] = leaky(hv);
    __syncthreads();
    for (int s=64; s>0; s>>=1){
        if (tid < s){
            #pragma unroll
            for (int j=0;j<NO;j++) red[tid][j] += red[tid+s][j];
        }
        __syncthreads();
    }
    if (tid < NO) zsh[tid] = expf(red[0][tid] + linr_b[tid]);
    __syncthreads();
    if (tid < NO){
        float zsum = 0.f;
        #pragma unroll
        for (int j=0;j<NO;j++) zsum += zsh[j];
        float z = zsh[tid] / (zsum + 1.f);
        float o = lino_b2[tid];
        for (int cc=0; cc<HC; cc++) o += hsh[cc]*lino_w2[cc*NO + tid];
        out[b*NO + tid] = z * expf(o);
    }
}

extern "C" void kernel_launch(void* const* d_in, const int* in_sizes, int n_in,
                              void* d_out, int out_size, void* d_ws, size_t ws_size,
                              hipStream_t stream) {
    const float* s_x     = (const float*)d_in[0];
    const float* r_x     = (const float*)d_in[1];
    const int*   ei      = (const int*)d_in[2];
    const float* bn_s_w  = (const float*)d_in[3];
    const float* bn_s_b  = (const float*)d_in[4];
    const float* bn_r_w  = (const float*)d_in[5];
    const float* bn_r_b  = (const float*)d_in[6];
    const float* lin_s_w = (const float*)d_in[7];
    const float* lin_r_w = (const float*)d_in[8];
    const float* conv_w  = (const float*)d_in[9];
    const float* conv_b  = (const float*)d_in[10];
    const float* linr_w  = (const float*)d_in[11];
    const float* linr_b  = (const float*)d_in[12];
    const float* lino_w1 = (const float*)d_in[13];
    const float* lino_b1 = (const float*)d_in[14];
    const float* lino_w2 = (const float*)d_in[15];
    const float* lino_b2 = (const float*)d_in[16];
    float* out = (float*)d_out;

    char* ws = (char*)d_ws;
    size_t off = 0;
    auto alloc = [&](size_t bytes)->void*{
        void* p = ws + off;
        off = (off + bytes + 255) & ~(size_t)255;
        return p;
    };
    float* x        = (float*)alloc((size_t)NN*HC*4);
    float* xw       = (float*)alloc((size_t)NN*HC*4);
    int*   cnt      = (int*)  alloc((size_t)NN*4);
    float* dinv     = (float*)alloc((size_t)NN*4);
    int*   rp       = (int*)  alloc((size_t)(NN+1)*4);
    int*   cursor   = (int*)  alloc((size_t)NN*4);
    int2*  csr      = (int2*) alloc((size_t)EE*8);
    float* stats    = (float*)alloc(64*4);
    int*   bsum     = (int*)  alloc(256*4);
    float* pooled   = (float*)alloc((size_t)NN*4);

    hipMemsetAsync(cnt, 0, (size_t)NN*4, stream);
    hipMemsetAsync(stats, 0, 64*4, stream);

    stats_s_kernel<<<(NS+255)/256, 256, 0, stream>>>(s_x, stats);
    stats_r_kernel<<<(NR+255)/256, 256, 0, stream>>>(r_x, stats);
    finalize_stats_kernel<<<1, 64, 0, stream>>>(stats, bn_s_w, bn_s_b, bn_r_w, bn_r_b);
    feature_kernel<<<NN/2, 256, 0, stream>>>(s_x, r_x, stats, lin_s_w, lin_r_w, x);

    count_kernel<<<EE/256, 256, 0, stream>>>(ei + EE, cnt);
    scan_block_kernel<<<SCAN_NB, 1024, 0, stream>>>(cnt, rp, bsum);
    scan_sums_kernel<<<1, 1, 0, stream>>>(bsum, rp);
    offsets_kernel<<<NN/256, 256, 0, stream>>>(rp, bsum, cnt, cursor, dinv);
    scatter_kernel<<<EE/256, 256, 0, stream>>>(ei, ei + EE, dinv, cursor, csr);

    for (int l = 0; l < LCONV; l++){
        gemm_kernel<<<dim3(NN/64, 2), 256, 0, stream>>>(x, conv_w + (size_t)l*HC*HC, xw);
        agg_kernel<<<NN/2, 256, 0, stream>>>(xw, rp, csr, dinv, conv_b + (size_t)l*HC, x);
    }

    pool_kernel<<<NN/4, 256, 0, stream>>>(x, pooled);
    head_kernel<<<BATCH, 128, 0, stream>>>(pooled, r_x, linr_w, linr_b,
                                           lino_w1, lino_b1, lino_w2, lino_b2, out);
}

// Round 2
// 1884.032 us; speedup vs baseline: 1.6601x; 1.6601x over previous
//
#include <hip/hip_runtime.h>
#include <hip/hip_bf16.h>

#define SDIM 38
#define RDIM 340
#define HC   128
#define SC   4
#define RC   3
#define NO   7
#define LCONV 4
#define BATCH 512
#define SR   378
#define NN   (BATCH*SR)     // 193536
#define NS   (BATCH*SDIM)   // 19456
#define NR   (BATCH*RDIM)   // 174080
#define EE   3072000
#define EPSV 1e-5f
#define SCAN_NB 189         // NN/1024

__device__ __forceinline__ float leaky(float v){ return v > 0.f ? v : 0.2f*v; }

// ---------------- batchnorm stats ----------------
__global__ void stats_s_kernel(const float* __restrict__ s_x, float* __restrict__ stats){
    int tid = threadIdx.x;
    int r = blockIdx.x*256 + tid;
    float4 v = make_float4(0.f,0.f,0.f,0.f);
    if (r < NS) v = *(const float4*)(s_x + (size_t)r*SC);
    __shared__ float sh[256][8];
    sh[tid][0]=v.x; sh[tid][1]=v.y; sh[tid][2]=v.z; sh[tid][3]=v.w;
    sh[tid][4]=v.x*v.x; sh[tid][5]=v.y*v.y; sh[tid][6]=v.z*v.z; sh[tid][7]=v.w*v.w;
    __syncthreads();
    for (int s=128; s>0; s>>=1){
        if (tid < s){
            #pragma unroll
            for (int k=0;k<8;k++) sh[tid][k]+=sh[tid+s][k];
        }
        __syncthreads();
    }
    if (tid < 8) atomicAdd(&stats[tid], sh[0][tid]);
}

__global__ void stats_r_kernel(const float* __restrict__ r_x, float* __restrict__ stats){
    int tid = threadIdx.x;
    int r = blockIdx.x*256 + tid;
    float4 v = make_float4(0.f,0.f,0.f,0.f);
    if (r < NR) v = *(const float4*)(r_x + (size_t)r*8);
    __shared__ float sh[256][8];
    sh[tid][0]=v.x; sh[tid][1]=v.y; sh[tid][2]=v.z;
    sh[tid][3]=v.x*v.x; sh[tid][4]=v.y*v.y; sh[tid][5]=v.z*v.z;
    sh[tid][6]=0.f; sh[tid][7]=0.f;
    __syncthreads();
    for (int s=128; s>0; s>>=1){
        if (tid < s){
            #pragma unroll
            for (int k=0;k<6;k++) sh[tid][k]+=sh[tid+s][k];
        }
        __syncthreads();
    }
    if (tid < 6) atomicAdd(&stats[8+tid], sh[0][tid]);
}

__global__ void finalize_stats_kernel(float* __restrict__ st,
        const float* __restrict__ bn_s_w, const float* __restrict__ bn_s_b,
        const float* __restrict__ bn_r_w, const float* __restrict__ bn_r_b){
    int t = threadIdx.x;
    if (t < SC){
        float m  = st[t] * (1.f/NS);
        float var= st[4+t] * (1.f/NS) - m*m;
        float sc = rsqrtf(var + EPSV) * bn_s_w[t];
        st[16+t] = sc; st[20+t] = bn_s_b[t] - m*sc;
    } else if (t >= 8 && t < 8+RC){
        int k = t-8;
        float m  = st[8+k] * (1.f/NR);
        float var= st[11+k] * (1.f/NR) - m*m;
        float sc = rsqrtf(var + EPSV) * bn_r_w[k];
        st[24+k] = sc; st[27+k] = bn_r_b[k] - m*sc;
    }
}

// ---------------- node features ----------------
__global__ void feature_kernel(const float* __restrict__ s_x, const float* __restrict__ r_x,
        const float* __restrict__ stats, const float* __restrict__ lin_s_w,
        const float* __restrict__ lin_r_w, float* __restrict__ x){
    int node = blockIdx.x*2 + (threadIdx.x >> 7);
    int c = threadIdx.x & 127;
    int b = node / SR;
    int p = node - b*SR;
    float acc;
    if (p < SDIM){
        int row = b*SDIM + p;
        float4 v = *(const float4*)(s_x + (size_t)row*SC);
        float i0 = v.x*stats[16]+stats[20];
        float i1 = v.y*stats[17]+stats[21];
        float i2 = v.z*stats[18]+stats[22];
        float i3 = v.w*stats[19]+stats[23];
        acc = i0*lin_s_w[0*HC+c] + i1*lin_s_w[1*HC+c] + i2*lin_s_w[2*HC+c] + i3*lin_s_w[3*HC+c];
    } else {
        int row = b*RDIM + (p - SDIM);
        float4 v = *(const float4*)(r_x + (size_t)row*8);
        float i0 = v.x*stats[24]+stats[27];
        float i1 = v.y*stats[25]+stats[28];
        float i2 = v.z*stats[26]+stats[29];
        acc = i0*lin_r_w[0*HC+c] + i1*lin_r_w[1*HC+c] + i2*lin_r_w[2*HC+c];
    }
    x[(size_t)node*HC + c] = leaky(acc);
}

// ---------------- degree / CSR build ----------------
__global__ void count_kernel(const int* __restrict__ dst, int* __restrict__ cnt){
    int e = blockIdx.x*256 + threadIdx.x;
    atomicAdd(&cnt[dst[e]], 1);
}

__global__ void scan_block_kernel(const int* __restrict__ cnt, int* __restrict__ rp,
                                  int* __restrict__ bsum){
    __shared__ int sh[1024];
    int tid = threadIdx.x;
    int i = blockIdx.x*1024 + tid;
    int v = cnt[i];
    sh[tid] = v;
    __syncthreads();
    for (int off=1; off<1024; off<<=1){
        int t = (tid >= off) ? sh[tid-off] : 0;
        __syncthreads();
        sh[tid] += t;
        __syncthreads();
    }
    rp[i] = sh[tid] - v;                 // exclusive within block
    if (tid == 1023) bsum[blockIdx.x] = sh[1023];
}

__global__ void scan_sums_kernel(int* __restrict__ bsum, int* __restrict__ rp){
    int run = 0;
    for (int b=0;b<SCAN_NB;b++){ int t = bsum[b]; bsum[b] = run; run += t; }
    rp[NN] = run;
}

__global__ void offsets_kernel(int* __restrict__ rp, const int* __restrict__ bsum,
        const int* __restrict__ cnt, int* __restrict__ cursor, float* __restrict__ dinv){
    int i = blockIdx.x*256 + threadIdx.x;   // grid = NN/256 exact
    int r = rp[i] + bsum[i >> 10];
    rp[i] = r; cursor[i] = r;
    dinv[i] = rsqrtf((float)(cnt[i] + 1));  // +1 self loop
}

__global__ void scatter_kernel(const int* __restrict__ src, const int* __restrict__ dst,
        const float* __restrict__ dinv, int* __restrict__ cursor, int2* __restrict__ csr){
    int e = blockIdx.x*256 + threadIdx.x;
    int s = src[e], d = dst[e];
    int pos = atomicAdd(&cursor[d], 1);
    csr[pos] = make_int2(s, __float_as_int(dinv[s]*dinv[d]));
}

// ---------------- conv GEMM: xw = x @ W  (fp32, LDS-tiled) ----------------
__global__ __launch_bounds__(256) void gemm_kernel(const float* __restrict__ x,
        const float* __restrict__ Wg, float* __restrict__ xw){
    __shared__ float Ws[128*64];      // [k][c] pitch 64, 32 KB
    __shared__ float xs[64*66];       // [r][k-half] pitch 66, 16.9 KB
    int tid = threadIdx.x;
    int rowbase = blockIdx.x * 64;
    int colbase = blockIdx.y * 64;
    // stage W half (128 x 64)
    for (int idx = tid; idx < 128*64; idx += 256){
        int k = idx >> 6, c = idx & 63;
        Ws[idx] = Wg[k*HC + colbase + c];
    }
    int cg = tid & 15, rg = tid >> 4;
    int c0 = cg*4, r0 = rg*4;
    float acc[4][4];
    #pragma unroll
    for (int i=0;i<4;i++){ acc[i][0]=0.f; acc[i][1]=0.f; acc[i][2]=0.f; acc[i][3]=0.f; }
    for (int kk = 0; kk < 128; kk += 64){
        __syncthreads();
        for (int idx = tid; idx < 64*64; idx += 256){
            int r = idx >> 6, k = idx & 63;
            xs[r*66 + k] = x[(size_t)(rowbase + r)*HC + kk + k];
        }
        __syncthreads();
        #pragma unroll 8
        for (int k = 0; k < 64; k++){
            float4 w4 = *(const float4*)&Ws[(kk + k)*64 + c0];
            float x0 = xs[(r0+0)*66 + k];
            float x1 = xs[(r0+1)*66 + k];
            float x2 = xs[(r0+2)*66 + k];
            float x3 = xs[(r0+3)*66 + k];
            acc[0][0]+=x0*w4.x; acc[0][1]+=x0*w4.y; acc[0][2]+=x0*w4.z; acc[0][3]+=x0*w4.w;
            acc[1][0]+=x1*w4.x; acc[1][1]+=x1*w4.y; acc[1][2]+=x1*w4.z; acc[1][3]+=x1*w4.w;
            acc[2][0]+=x2*w4.x; acc[2][1]+=x2*w4.y; acc[2][2]+=x2*w4.z; acc[2][3]+=x2*w4.w;
            acc[3][0]+=x3*w4.x; acc[3][1]+=x3*w4.y; acc[3][2]+=x3*w4.z; acc[3][3]+=x3*w4.w;
        }
    }
    #pragma unroll
    for (int i=0;i<4;i++){
        float4 o = make_float4(acc[i][0], acc[i][1], acc[i][2], acc[i][3]);
        *(float4*)&xw[(size_t)(rowbase + r0 + i)*HC + colbase + c0] = o;
    }
}

// ---------------- aggregation: x += leaky(A_norm @ xw + b) ----------------
// one wave per node; lane = (half:1)(chquad:5); 2 edges per load instr, unroll 2
__global__ __launch_bounds__(256) void agg_kernel(const float* __restrict__ xw,
        const int* __restrict__ rp, const int2* __restrict__ csr,
        const float* __restrict__ dinv, const float* __restrict__ bias,
        float* __restrict__ x){
    int lane = threadIdx.x & 63;
    int node = blockIdx.x*4 + (threadIdx.x >> 6);
    int half = lane >> 5;           // edge parity for this lane
    int c4 = (lane & 31) * 4;       // channel quad
    int beg = rp[node], end = rp[node+1];

    float4 acc0 = make_float4(0.f,0.f,0.f,0.f);
    float4 acc1 = make_float4(0.f,0.f,0.f,0.f);

    int j = beg + half;
    while (j + 2 < end){
        int2 e0 = csr[j];
        int2 e1 = csr[j+2];
        float4 v0 = *(const float4*)(xw + (size_t)e0.x*HC + c4);
        float4 v1 = *(const float4*)(xw + (size_t)e1.x*HC + c4);
        float w0 = __int_as_float(e0.y);
        float w1 = __int_as_float(e1.y);
        acc0.x += w0*v0.x; acc0.y += w0*v0.y; acc0.z += w0*v0.z; acc0.w += w0*v0.w;
        acc1.x += w1*v1.x; acc1.y += w1*v1.y; acc1.z += w1*v1.z; acc1.w += w1*v1.w;
        j += 4;
    }
    if (j < end){
        int2 e = csr[j];
        float4 v = *(const float4*)(xw + (size_t)e.x*HC + c4);
        float w = __int_as_float(e.y);
        acc0.x += w*v.x; acc0.y += w*v.y; acc0.z += w*v.z; acc0.w += w*v.w;
    }
    // merge local accumulators
    acc0.x += acc1.x; acc0.y += acc1.y; acc0.z += acc1.z; acc0.w += acc1.w;
    // self loop (half0 only contributes; add before cross-half combine on half0)
    if (half == 0){
        float dn = dinv[node];
        float4 sv = *(const float4*)(xw + (size_t)node*HC + c4);
        float sw = dn*dn;
        acc0.x += sw*sv.x; acc0.y += sw*sv.y; acc0.z += sw*sv.z; acc0.w += sw*sv.w;
    }
    // cross-half combine: lanes 0..31 += lanes 32..63
    acc0.x += __shfl_down(acc0.x, 32, 64);
    acc0.y += __shfl_down(acc0.y, 32, 64);
    acc0.z += __shfl_down(acc0.z, 32, 64);
    acc0.w += __shfl_down(acc0.w, 32, 64);
    if (half == 0){
        float4 b4 = *(const float4*)(bias + c4);
        size_t idx = (size_t)node*HC + c4;
        float4 xv = *(const float4*)(x + idx);
        xv.x += leaky(acc0.x + b4.x);
        xv.y += leaky(acc0.y + b4.y);
        xv.z += leaky(acc0.z + b4.z);
        xv.w += leaky(acc0.w + b4.w);
        *(float4*)(x + idx) = xv;
    }
}

// ---------------- channel-mean pool ----------------
__global__ void pool_kernel(const float* __restrict__ x, float* __restrict__ pooled){
    int wid = threadIdx.x >> 6;
    int lane = threadIdx.x & 63;
    int node = blockIdx.x*4 + wid;
    const float* row = x + (size_t)node*HC;
    float v = row[lane] + row[64 + lane];
    #pragma unroll
    for (int off=32; off>0; off>>=1) v += __shfl_down(v, off, 64);
    if (lane == 0) pooled[node] = v * (1.f/128.f);
}

// ---------------- heads: z, o, output ----------------
__global__ void head_kernel(const float* __restrict__ pooled, const float* __restrict__ r_x,
        const float* __restrict__ linr_w, const float* __restrict__ linr_b,
        const float* __restrict__ lino_w1, const float* __restrict__ lino_b1,
        const float* __restrict__ lino_w2, const float* __restrict__ lino_b2,
        float* __restrict__ out){
    int b = blockIdx.x, tid = threadIdx.x;
    __shared__ float red[128][8];
    __shared__ float hsh[128];
    __shared__ float zsh[8];
    float part[NO];
    #pragma unroll
    for (int j=0;j<NO;j++) part[j]=0.f;
    for (int i = tid; i < SR; i += 128){
        float pv = pooled[(size_t)b*SR + i];
        #pragma unroll
        for (int j=0;j<NO;j++) part[j] += pv * linr_w[i*NO + j];
    }
    #pragma unroll
    for (int j=0;j<NO;j++) red[tid][j] = part[j];
    // o path: h[c]
    const float* ox = r_x + (size_t)b*RDIM*8 + RC;
    float hv = lino_b1[tid];
    #pragma unroll
    for (int k=0;k<5;k++) hv += ox[k]*lino_w1[k*HC + tid];
    hsh[tid] = leaky(hv);
    __syncthreads();
    for (int s=64; s>0; s>>=1){
        if (tid < s){
            #pragma unroll
            for (int j=0;j<NO;j++) red[tid][j] += red[tid+s][j];
        }
        __syncthreads();
    }
    if (tid < NO) zsh[tid] = expf(red[0][tid] + linr_b[tid]);
    __syncthreads();
    if (tid < NO){
        float zsum = 0.f;
        #pragma unroll
        for (int j=0;j<NO;j++) zsum += zsh[j];
        float z = zsh[tid] / (zsum + 1.f);
        float o = lino_b2[tid];
        for (int cc=0; cc<HC; cc++) o += hsh[cc]*lino_w2[cc*NO + tid];
        out[b*NO + tid] = z * expf(o);
    }
}

extern "C" void kernel_launch(void* const* d_in, const int* in_sizes, int n_in,
                              void* d_out, int out_size, void* d_ws, size_t ws_size,
                              hipStream_t stream) {
    const float* s_x     = (const float*)d_in[0];
    const float* r_x     = (const float*)d_in[1];
    const int*   ei      = (const int*)d_in[2];
    const float* bn_s_w  = (const float*)d_in[3];
    const float* bn_s_b  = (const float*)d_in[4];
    const float* bn_r_w  = (const float*)d_in[5];
    const float* bn_r_b  = (const float*)d_in[6];
    const float* lin_s_w = (const float*)d_in[7];
    const float* lin_r_w = (const float*)d_in[8];
    const float* conv_w  = (const float*)d_in[9];
    const float* conv_b  = (const float*)d_in[10];
    const float* linr_w  = (const float*)d_in[11];
    const float* linr_b  = (const float*)d_in[12];
    const float* lino_w1 = (const float*)d_in[13];
    const float* lino_b1 = (const float*)d_in[14];
    const float* lino_w2 = (const float*)d_in[15];
    const float* lino_b2 = (const float*)d_in[16];
    float* out = (float*)d_out;

    char* ws = (char*)d_ws;
    size_t off = 0;
    auto alloc = [&](size_t bytes)->void*{
        void* p = ws + off;
        off = (off + bytes + 255) & ~(size_t)255;
        return p;
    };
    float* x        = (float*)alloc((size_t)NN*HC*4);
    float* xw       = (float*)alloc((size_t)NN*HC*4);
    int*   cnt      = (int*)  alloc((size_t)NN*4);
    float* dinv     = (float*)alloc((size_t)NN*4);
    int*   rp       = (int*)  alloc((size_t)(NN+1)*4);
    int*   cursor   = (int*)  alloc((size_t)NN*4);
    int2*  csr      = (int2*) alloc((size_t)EE*8);
    float* stats    = (float*)alloc(64*4);
    int*   bsum     = (int*)  alloc(256*4);
    float* pooled   = (float*)alloc((size_t)NN*4);

    hipMemsetAsync(cnt, 0, (size_t)NN*4, stream);
    hipMemsetAsync(stats, 0, 64*4, stream);

    stats_s_kernel<<<(NS+255)/256, 256, 0, stream>>>(s_x, stats);
    stats_r_kernel<<<(NR+255)/256, 256, 0, stream>>>(r_x, stats);
    finalize_stats_kernel<<<1, 64, 0, stream>>>(stats, bn_s_w, bn_s_b, bn_r_w, bn_r_b);
    feature_kernel<<<NN/2, 256, 0, stream>>>(s_x, r_x, stats, lin_s_w, lin_r_w, x);

    count_kernel<<<EE/256, 256, 0, stream>>>(ei + EE, cnt);
    scan_block_kernel<<<SCAN_NB, 1024, 0, stream>>>(cnt, rp, bsum);
    scan_sums_kernel<<<1, 1, 0, stream>>>(bsum, rp);
    offsets_kernel<<<NN/256, 256, 0, stream>>>(rp, bsum, cnt, cursor, dinv);
    scatter_kernel<<<EE/256, 256, 0, stream>>>(ei, ei + EE, dinv, cursor, csr);

    for (int l = 0; l < LCONV; l++){
        gemm_kernel<<<dim3(NN/64, 2), 256, 0, stream>>>(x, conv_w + (size_t)l*HC*HC, xw);
        agg_kernel<<<NN/4, 256, 0, stream>>>(xw, rp, csr, dinv, conv_b + (size_t)l*HC, x);
    }

    pool_kernel<<<NN/4, 256, 0, stream>>>(x, pooled);
    head_kernel<<<BATCH, 128, 0, stream>>>(pooled, r_x, linr_w, linr_b,
                                           lino_w1, lino_b1, lino_w2, lino_b2, out);
}

// Round 3
// 1546.283 us; speedup vs baseline: 2.0228x; 1.2184x over previous
//
#include <hip/hip_runtime.h>
#include <hip/hip_bf16.h>

#define SDIM 38
#define RDIM 340
#define HC   128
#define SC   4
#define RC   3
#define NO   7
#define LCONV 4
#define BATCH 512
#define SR   378
#define NN   (BATCH*SR)     // 193536
#define NS   (BATCH*SDIM)   // 19456
#define NR   (BATCH*RDIM)   // 174080
#define EE   3072000
#define EPSV 1e-5f
#define SCAN_NB 189         // NN/1024

__device__ __forceinline__ float leaky(float v){ return v > 0.f ? v : 0.2f*v; }

// round-to-nearest-even fp32 -> bf16 (as ushort)
__device__ __forceinline__ unsigned short f2bf(float f){
    union { float f; unsigned u; } v; v.f = f;
    unsigned r = v.u + 0x7fffu + ((v.u >> 16) & 1u);
    return (unsigned short)(r >> 16);
}
// unpack 4 bf16 (uint2) -> float4
__device__ __forceinline__ float4 bf4_to_f4(uint2 p){
    float4 r;
    r.x = __uint_as_float(p.x << 16);
    r.y = __uint_as_float(p.x & 0xffff0000u);
    r.z = __uint_as_float(p.y << 16);
    r.w = __uint_as_float(p.y & 0xffff0000u);
    return r;
}

// ---------------- batchnorm stats ----------------
__global__ void stats_s_kernel(const float* __restrict__ s_x, float* __restrict__ stats){
    int tid = threadIdx.x;
    int r = blockIdx.x*256 + tid;
    float4 v = make_float4(0.f,0.f,0.f,0.f);
    if (r < NS) v = *(const float4*)(s_x + (size_t)r*SC);
    __shared__ float sh[256][8];
    sh[tid][0]=v.x; sh[tid][1]=v.y; sh[tid][2]=v.z; sh[tid][3]=v.w;
    sh[tid][4]=v.x*v.x; sh[tid][5]=v.y*v.y; sh[tid][6]=v.z*v.z; sh[tid][7]=v.w*v.w;
    __syncthreads();
    for (int s=128; s>0; s>>=1){
        if (tid < s){
            #pragma unroll
            for (int k=0;k<8;k++) sh[tid][k]+=sh[tid+s][k];
        }
        __syncthreads();
    }
    if (tid < 8) atomicAdd(&stats[tid], sh[0][tid]);
}

__global__ void stats_r_kernel(const float* __restrict__ r_x, float* __restrict__ stats){
    int tid = threadIdx.x;
    int r = blockIdx.x*256 + tid;
    float4 v = make_float4(0.f,0.f,0.f,0.f);
    if (r < NR) v = *(const float4*)(r_x + (size_t)r*8);
    __shared__ float sh[256][8];
    sh[tid][0]=v.x; sh[tid][1]=v.y; sh[tid][2]=v.z;
    sh[tid][3]=v.x*v.x; sh[tid][4]=v.y*v.y; sh[tid][5]=v.z*v.z;
    sh[tid][6]=0.f; sh[tid][7]=0.f;
    __syncthreads();
    for (int s=128; s>0; s>>=1){
        if (tid < s){
            #pragma unroll
            for (int k=0;k<6;k++) sh[tid][k]+=sh[tid+s][k];
        }
        __syncthreads();
    }
    if (tid < 6) atomicAdd(&stats[8+tid], sh[0][tid]);
}

__global__ void finalize_stats_kernel(float* __restrict__ st,
        const float* __restrict__ bn_s_w, const float* __restrict__ bn_s_b,
        const float* __restrict__ bn_r_w, const float* __restrict__ bn_r_b){
    int t = threadIdx.x;
    if (t < SC){
        float m  = st[t] * (1.f/NS);
        float var= st[4+t] * (1.f/NS) - m*m;
        float sc = rsqrtf(var + EPSV) * bn_s_w[t];
        st[16+t] = sc; st[20+t] = bn_s_b[t] - m*sc;
    } else if (t >= 8 && t < 8+RC){
        int k = t-8;
        float m  = st[8+k] * (1.f/NR);
        float var= st[11+k] * (1.f/NR) - m*m;
        float sc = rsqrtf(var + EPSV) * bn_r_w[k];
        st[24+k] = sc; st[27+k] = bn_r_b[k] - m*sc;
    }
}

// ---------------- node features ----------------
__global__ void feature_kernel(const float* __restrict__ s_x, const float* __restrict__ r_x,
        const float* __restrict__ stats, const float* __restrict__ lin_s_w,
        const float* __restrict__ lin_r_w, float* __restrict__ x){
    int node = blockIdx.x*2 + (threadIdx.x >> 7);
    int c = threadIdx.x & 127;
    int b = node / SR;
    int p = node - b*SR;
    float acc;
    if (p < SDIM){
        int row = b*SDIM + p;
        float4 v = *(const float4*)(s_x + (size_t)row*SC);
        float i0 = v.x*stats[16]+stats[20];
        float i1 = v.y*stats[17]+stats[21];
        float i2 = v.z*stats[18]+stats[22];
        float i3 = v.w*stats[19]+stats[23];
        acc = i0*lin_s_w[0*HC+c] + i1*lin_s_w[1*HC+c] + i2*lin_s_w[2*HC+c] + i3*lin_s_w[3*HC+c];
    } else {
        int row = b*RDIM + (p - SDIM);
        float4 v = *(const float4*)(r_x + (size_t)row*8);
        float i0 = v.x*stats[24]+stats[27];
        float i1 = v.y*stats[25]+stats[28];
        float i2 = v.z*stats[26]+stats[29];
        acc = i0*lin_r_w[0*HC+c] + i1*lin_r_w[1*HC+c] + i2*lin_r_w[2*HC+c];
    }
    x[(size_t)node*HC + c] = leaky(acc);
}

// ---------------- degree / CSR build ----------------
__global__ void count_kernel(const int* __restrict__ dst, int* __restrict__ cnt){
    int e = blockIdx.x*256 + threadIdx.x;
    atomicAdd(&cnt[dst[e]], 1);
}

__global__ void scan_block_kernel(const int* __restrict__ cnt, int* __restrict__ rp,
                                  int* __restrict__ bsum){
    __shared__ int sh[1024];
    int tid = threadIdx.x;
    int i = blockIdx.x*1024 + tid;
    int v = cnt[i];
    sh[tid] = v;
    __syncthreads();
    for (int off=1; off<1024; off<<=1){
        int t = (tid >= off) ? sh[tid-off] : 0;
        __syncthreads();
        sh[tid] += t;
        __syncthreads();
    }
    rp[i] = sh[tid] - v;                 // exclusive within block
    if (tid == 1023) bsum[blockIdx.x] = sh[1023];
}

__global__ void scan_sums_kernel(int* __restrict__ bsum, int* __restrict__ rp){
    int run = 0;
    for (int b=0;b<SCAN_NB;b++){ int t = bsum[b]; bsum[b] = run; run += t; }
    rp[NN] = run;
}

__global__ void offsets_kernel(int* __restrict__ rp, const int* __restrict__ bsum,
        const int* __restrict__ cnt, int* __restrict__ cursor, float* __restrict__ dinv){
    int i = blockIdx.x*256 + threadIdx.x;   // grid = NN/256 exact
    int r = rp[i] + bsum[i >> 10];
    rp[i] = r; cursor[i] = r;
    dinv[i] = rsqrtf((float)(cnt[i] + 1));  // +1 self loop
}

__global__ void scatter_kernel(const int* __restrict__ src, const int* __restrict__ dst,
        const float* __restrict__ dinv, int* __restrict__ cursor, int2* __restrict__ csr){
    int e = blockIdx.x*256 + threadIdx.x;
    int s = src[e], d = dst[e];
    int pos = atomicAdd(&cursor[d], 1);
    csr[pos] = make_int2(s, __float_as_int(dinv[s]*dinv[d]));
}

// ---------------- conv GEMM: xw = x @ W  (fp32 math, bf16 store) ----------------
__global__ __launch_bounds__(256) void gemm_kernel(const float* __restrict__ x,
        const float* __restrict__ Wg, unsigned short* __restrict__ xw){
    __shared__ float Ws[128*64];      // [k][c] pitch 64, 32 KB
    __shared__ float xs[64*66];       // [r][k-half] pitch 66, 16.9 KB
    int tid = threadIdx.x;
    int rowbase = blockIdx.x * 64;
    int colbase = blockIdx.y * 64;
    // stage W half (128 x 64)
    for (int idx = tid; idx < 128*64; idx += 256){
        int k = idx >> 6, c = idx & 63;
        Ws[idx] = Wg[k*HC + colbase + c];
    }
    int cg = tid & 15, rg = tid >> 4;
    int c0 = cg*4, r0 = rg*4;
    float acc[4][4];
    #pragma unroll
    for (int i=0;i<4;i++){ acc[i][0]=0.f; acc[i][1]=0.f; acc[i][2]=0.f; acc[i][3]=0.f; }
    for (int kk = 0; kk < 128; kk += 64){
        __syncthreads();
        for (int idx = tid; idx < 64*64; idx += 256){
            int r = idx >> 6, k = idx & 63;
            xs[r*66 + k] = x[(size_t)(rowbase + r)*HC + kk + k];
        }
        __syncthreads();
        #pragma unroll 8
        for (int k = 0; k < 64; k++){
            float4 w4 = *(const float4*)&Ws[(kk + k)*64 + c0];
            float x0 = xs[(r0+0)*66 + k];
            float x1 = xs[(r0+1)*66 + k];
            float x2 = xs[(r0+2)*66 + k];
            float x3 = xs[(r0+3)*66 + k];
            acc[0][0]+=x0*w4.x; acc[0][1]+=x0*w4.y; acc[0][2]+=x0*w4.z; acc[0][3]+=x0*w4.w;
            acc[1][0]+=x1*w4.x; acc[1][1]+=x1*w4.y; acc[1][2]+=x1*w4.z; acc[1][3]+=x1*w4.w;
            acc[2][0]+=x2*w4.x; acc[2][1]+=x2*w4.y; acc[2][2]+=x2*w4.z; acc[2][3]+=x2*w4.w;
            acc[3][0]+=x3*w4.x; acc[3][1]+=x3*w4.y; acc[3][2]+=x3*w4.z; acc[3][3]+=x3*w4.w;
        }
    }
    #pragma unroll
    for (int i=0;i<4;i++){
        uint2 o;
        o.x = (unsigned)f2bf(acc[i][0]) | ((unsigned)f2bf(acc[i][1]) << 16);
        o.y = (unsigned)f2bf(acc[i][2]) | ((unsigned)f2bf(acc[i][3]) << 16);
        *(uint2*)&xw[(size_t)(rowbase + r0 + i)*HC + colbase + c0] = o;
    }
}

// ---------------- aggregation: x += leaky(A_norm @ xw + b), xw in bf16 ----------------
// one wave per node; lane = (half:1)(chquad:5); 2 edges per load instr, unroll 2
__global__ __launch_bounds__(256) void agg_kernel(const unsigned short* __restrict__ xw,
        const int* __restrict__ rp, const int2* __restrict__ csr,
        const float* __restrict__ dinv, const float* __restrict__ bias,
        float* __restrict__ x){
    int lane = threadIdx.x & 63;
    int node = blockIdx.x*4 + (threadIdx.x >> 6);
    int half = lane >> 5;           // edge parity for this lane
    int c4 = (lane & 31) * 4;       // channel quad
    int beg = rp[node], end = rp[node+1];

    float4 acc0 = make_float4(0.f,0.f,0.f,0.f);
    float4 acc1 = make_float4(0.f,0.f,0.f,0.f);

    int j = beg + half;
    while (j + 2 < end){
        int2 e0 = csr[j];
        int2 e1 = csr[j+2];
        uint2 p0 = *(const uint2*)(xw + (size_t)e0.x*HC + c4);
        uint2 p1 = *(const uint2*)(xw + (size_t)e1.x*HC + c4);
        float4 v0 = bf4_to_f4(p0);
        float4 v1 = bf4_to_f4(p1);
        float w0 = __int_as_float(e0.y);
        float w1 = __int_as_float(e1.y);
        acc0.x += w0*v0.x; acc0.y += w0*v0.y; acc0.z += w0*v0.z; acc0.w += w0*v0.w;
        acc1.x += w1*v1.x; acc1.y += w1*v1.y; acc1.z += w1*v1.z; acc1.w += w1*v1.w;
        j += 4;
    }
    if (j < end){
        int2 e = csr[j];
        float4 v = bf4_to_f4(*(const uint2*)(xw + (size_t)e.x*HC + c4));
        float w = __int_as_float(e.y);
        acc0.x += w*v.x; acc0.y += w*v.y; acc0.z += w*v.z; acc0.w += w*v.w;
    }
    // merge local accumulators
    acc0.x += acc1.x; acc0.y += acc1.y; acc0.z += acc1.z; acc0.w += acc1.w;
    // self loop (half0 only contributes; add before cross-half combine on half0)
    if (half == 0){
        float dn = dinv[node];
        float4 sv = bf4_to_f4(*(const uint2*)(xw + (size_t)node*HC + c4));
        float sw = dn*dn;
        acc0.x += sw*sv.x; acc0.y += sw*sv.y; acc0.z += sw*sv.z; acc0.w += sw*sv.w;
    }
    // cross-half combine: lanes 0..31 += lanes 32..63
    acc0.x += __shfl_down(acc0.x, 32, 64);
    acc0.y += __shfl_down(acc0.y, 32, 64);
    acc0.z += __shfl_down(acc0.z, 32, 64);
    acc0.w += __shfl_down(acc0.w, 32, 64);
    if (half == 0){
        float4 b4 = *(const float4*)(bias + c4);
        size_t idx = (size_t)node*HC + c4;
        float4 xv = *(const float4*)(x + idx);
        xv.x += leaky(acc0.x + b4.x);
        xv.y += leaky(acc0.y + b4.y);
        xv.z += leaky(acc0.z + b4.z);
        xv.w += leaky(acc0.w + b4.w);
        *(float4*)(x + idx) = xv;
    }
}

// ---------------- channel-mean pool ----------------
__global__ void pool_kernel(const float* __restrict__ x, float* __restrict__ pooled){
    int wid = threadIdx.x >> 6;
    int lane = threadIdx.x & 63;
    int node = blockIdx.x*4 + wid;
    const float* row = x + (size_t)node*HC;
    float v = row[lane] + row[64 + lane];
    #pragma unroll
    for (int off=32; off>0; off>>=1) v += __shfl_down(v, off, 64);
    if (lane == 0) pooled[node] = v * (1.f/128.f);
}

// ---------------- heads: z, o, output ----------------
__global__ void head_kernel(const float* __restrict__ pooled, const float* __restrict__ r_x,
        const float* __restrict__ linr_w, const float* __restrict__ linr_b,
        const float* __restrict__ lino_w1, const float* __restrict__ lino_b1,
        const float* __restrict__ lino_w2, const float* __restrict__ lino_b2,
        float* __restrict__ out){
    int b = blockIdx.x, tid = threadIdx.x;
    __shared__ float red[128][8];
    __shared__ float hsh[128];
    __shared__ float zsh[8];
    float part[NO];
    #pragma unroll
    for (int j=0;j<NO;j++) part[j]=0.f;
    for (int i = tid; i < SR; i += 128){
        float pv = pooled[(size_t)b*SR + i];
        #pragma unroll
        for (int j=0;j<NO;j++) part[j] += pv * linr_w[i*NO + j];
    }
    #pragma unroll
    for (int j=0;j<NO;j++) red[tid][j] = part[j];
    // o path: h[c]
    const float* ox = r_x + (size_t)b*RDIM*8 + RC;
    float hv = lino_b1[tid];
    #pragma unroll
    for (int k=0;k<5;k++) hv += ox[k]*lino_w1[k*HC + tid];
    hsh[tid] = leaky(hv);
    __syncthreads();
    for (int s=64; s>0; s>>=1){
        if (tid < s){
            #pragma unroll
            for (int j=0;j<NO;j++) red[tid][j] += red[tid+s][j];
        }
        __syncthreads();
    }
    if (tid < NO) zsh[tid] = expf(red[0][tid] + linr_b[tid]);
    __syncthreads();
    if (tid < NO){
        float zsum = 0.f;
        #pragma unroll
        for (int j=0;j<NO;j++) zsum += zsh[j];
        float z = zsh[tid] / (zsum + 1.f);
        float o = lino_b2[tid];
        for (int cc=0; cc<HC; cc++) o += hsh[cc]*lino_w2[cc*NO + tid];
        out[b*NO + tid] = z * expf(o);
    }
}

extern "C" void kernel_launch(void* const* d_in, const int* in_sizes, int n_in,
                              void* d_out, int out_size, void* d_ws, size_t ws_size,
                              hipStream_t stream) {
    const float* s_x     = (const float*)d_in[0];
    const float* r_x     = (const float*)d_in[1];
    const int*   ei      = (const int*)d_in[2];
    const float* bn_s_w  = (const float*)d_in[3];
    const float* bn_s_b  = (const float*)d_in[4];
    const float* bn_r_w  = (const float*)d_in[5];
    const float* bn_r_b  = (const float*)d_in[6];
    const float* lin_s_w = (const float*)d_in[7];
    const float* lin_r_w = (const float*)d_in[8];
    const float* conv_w  = (const float*)d_in[9];
    const float* conv_b  = (const float*)d_in[10];
    const float* linr_w  = (const float*)d_in[11];
    const float* linr_b  = (const float*)d_in[12];
    const float* lino_w1 = (const float*)d_in[13];
    const float* lino_b1 = (const float*)d_in[14];
    const float* lino_w2 = (const float*)d_in[15];
    const float* lino_b2 = (const float*)d_in[16];
    float* out = (float*)d_out;

    char* ws = (char*)d_ws;
    size_t off = 0;
    auto alloc = [&](size_t bytes)->void*{
        void* p = ws + off;
        off = (off + bytes + 255) & ~(size_t)255;
        return p;
    };
    float* x        = (float*)alloc((size_t)NN*HC*4);
    unsigned short* xw = (unsigned short*)alloc((size_t)NN*HC*2);
    int*   cnt      = (int*)  alloc((size_t)NN*4);
    float* dinv     = (float*)alloc((size_t)NN*4);
    int*   rp       = (int*)  alloc((size_t)(NN+1)*4);
    int*   cursor   = (int*)  alloc((size_t)NN*4);
    int2*  csr      = (int2*) alloc((size_t)EE*8);
    float* stats    = (float*)alloc(64*4);
    int*   bsum     = (int*)  alloc(256*4);
    float* pooled   = (float*)alloc((size_t)NN*4);

    hipMemsetAsync(cnt, 0, (size_t)NN*4, stream);
    hipMemsetAsync(stats, 0, 64*4, stream);

    stats_s_kernel<<<(NS+255)/256, 256, 0, stream>>>(s_x, stats);
    stats_r_kernel<<<(NR+255)/256, 256, 0, stream>>>(r_x, stats);
    finalize_stats_kernel<<<1, 64, 0, stream>>>(stats, bn_s_w, bn_s_b, bn_r_w, bn_r_b);
    feature_kernel<<<NN/2, 256, 0, stream>>>(s_x, r_x, stats, lin_s_w, lin_r_w, x);

    count_kernel<<<EE/256, 256, 0, stream>>>(ei + EE, cnt);
    scan_block_kernel<<<SCAN_NB, 1024, 0, stream>>>(cnt, rp, bsum);
    scan_sums_kernel<<<1, 1, 0, stream>>>(bsum, rp);
    offsets_kernel<<<NN/256, 256, 0, stream>>>(rp, bsum, cnt, cursor, dinv);
    scatter_kernel<<<EE/256, 256, 0, stream>>>(ei, ei + EE, dinv, cursor, csr);

    for (int l = 0; l < LCONV; l++){
        gemm_kernel<<<dim3(NN/64, 2), 256, 0, stream>>>(x, conv_w + (size_t)l*HC*HC, xw);
        agg_kernel<<<NN/4, 256, 0, stream>>>(xw, rp, csr, dinv, conv_b + (size_t)l*HC, x);
    }

    pool_kernel<<<NN/4, 256, 0, stream>>>(x, pooled);
    head_kernel<<<BATCH, 128, 0, stream>>>(pooled, r_x, linr_w, linr_b,
                                           lino_w1, lino_b1, lino_w2, lino_b2, out);
}

// Round 4
// 1248.448 us; speedup vs baseline: 2.5053x; 1.2386x over previous
//
#include <hip/hip_runtime.h>
#include <hip/hip_bf16.h>

#define SDIM 38
#define RDIM 340
#define HC   128
#define SC   4
#define RC   3
#define NO   7
#define LCONV 4
#define BATCH 512
#define SR   378
#define NN   (BATCH*SR)     // 193536
#define NS   (BATCH*SDIM)   // 19456
#define NR   (BATCH*RDIM)   // 174080
#define EE   3072000
#define EPSV 1e-5f
#define SCAN_NB 189         // NN/1024

typedef short v8s __attribute__((ext_vector_type(8)));
typedef float v4f __attribute__((ext_vector_type(4)));

__device__ __forceinline__ float leaky(float v){ return v > 0.f ? v : 0.2f*v; }

// round-to-nearest-even fp32 -> bf16 (as ushort)
__device__ __forceinline__ unsigned short f2bf(float f){
    union { float f; unsigned u; } v; v.f = f;
    unsigned r = v.u + 0x7fffu + ((v.u >> 16) & 1u);
    return (unsigned short)(r >> 16);
}
// unpack 4 bf16 (uint2) -> float4
__device__ __forceinline__ float4 bf4_to_f4(uint2 p){
    float4 r;
    r.x = __uint_as_float(p.x << 16);
    r.y = __uint_as_float(p.x & 0xffff0000u);
    r.z = __uint_as_float(p.y << 16);
    r.w = __uint_as_float(p.y & 0xffff0000u);
    return r;
}

// ---------------- batchnorm stats ----------------
__global__ void stats_s_kernel(const float* __restrict__ s_x, float* __restrict__ stats){
    int tid = threadIdx.x;
    int r = blockIdx.x*256 + tid;
    float4 v = make_float4(0.f,0.f,0.f,0.f);
    if (r < NS) v = *(const float4*)(s_x + (size_t)r*SC);
    __shared__ float sh[256][8];
    sh[tid][0]=v.x; sh[tid][1]=v.y; sh[tid][2]=v.z; sh[tid][3]=v.w;
    sh[tid][4]=v.x*v.x; sh[tid][5]=v.y*v.y; sh[tid][6]=v.z*v.z; sh[tid][7]=v.w*v.w;
    __syncthreads();
    for (int s=128; s>0; s>>=1){
        if (tid < s){
            #pragma unroll
            for (int k=0;k<8;k++) sh[tid][k]+=sh[tid+s][k];
        }
        __syncthreads();
    }
    if (tid < 8) atomicAdd(&stats[tid], sh[0][tid]);
}

__global__ void stats_r_kernel(const float* __restrict__ r_x, float* __restrict__ stats){
    int tid = threadIdx.x;
    int r = blockIdx.x*256 + tid;
    float4 v = make_float4(0.f,0.f,0.f,0.f);
    if (r < NR) v = *(const float4*)(r_x + (size_t)r*8);
    __shared__ float sh[256][8];
    sh[tid][0]=v.x; sh[tid][1]=v.y; sh[tid][2]=v.z;
    sh[tid][3]=v.x*v.x; sh[tid][4]=v.y*v.y; sh[tid][5]=v.z*v.z;
    sh[tid][6]=0.f; sh[tid][7]=0.f;
    __syncthreads();
    for (int s=128; s>0; s>>=1){
        if (tid < s){
            #pragma unroll
            for (int k=0;k<6;k++) sh[tid][k]+=sh[tid+s][k];
        }
        __syncthreads();
    }
    if (tid < 6) atomicAdd(&stats[8+tid], sh[0][tid]);
}

__global__ void finalize_stats_kernel(float* __restrict__ st,
        const float* __restrict__ bn_s_w, const float* __restrict__ bn_s_b,
        const float* __restrict__ bn_r_w, const float* __restrict__ bn_r_b){
    int t = threadIdx.x;
    if (t < SC){
        float m  = st[t] * (1.f/NS);
        float var= st[4+t] * (1.f/NS) - m*m;
        float sc = rsqrtf(var + EPSV) * bn_s_w[t];
        st[16+t] = sc; st[20+t] = bn_s_b[t] - m*sc;
    } else if (t >= 8 && t < 8+RC){
        int k = t-8;
        float m  = st[8+k] * (1.f/NR);
        float var= st[11+k] * (1.f/NR) - m*m;
        float sc = rsqrtf(var + EPSV) * bn_r_w[k];
        st[24+k] = sc; st[27+k] = bn_r_b[k] - m*sc;
    }
}

// ---------------- node features (writes x fp32 + xb bf16) ----------------
__global__ void feature_kernel(const float* __restrict__ s_x, const float* __restrict__ r_x,
        const float* __restrict__ stats, const float* __restrict__ lin_s_w,
        const float* __restrict__ lin_r_w, float* __restrict__ x,
        unsigned short* __restrict__ xb){
    int node = blockIdx.x*4 + (threadIdx.x >> 6);
    int c0 = (threadIdx.x & 63) * 2;
    int b = node / SR;
    int p = node - b*SR;
    float a0, a1;
    if (p < SDIM){
        int row = b*SDIM + p;
        float4 v = *(const float4*)(s_x + (size_t)row*SC);
        float i0 = v.x*stats[16]+stats[20];
        float i1 = v.y*stats[17]+stats[21];
        float i2 = v.z*stats[18]+stats[22];
        float i3 = v.w*stats[19]+stats[23];
        a0 = i0*lin_s_w[c0] + i1*lin_s_w[HC+c0] + i2*lin_s_w[2*HC+c0] + i3*lin_s_w[3*HC+c0];
        a1 = i0*lin_s_w[c0+1] + i1*lin_s_w[HC+c0+1] + i2*lin_s_w[2*HC+c0+1] + i3*lin_s_w[3*HC+c0+1];
    } else {
        int row = b*RDIM + (p - SDIM);
        float4 v = *(const float4*)(r_x + (size_t)row*8);
        float i0 = v.x*stats[24]+stats[27];
        float i1 = v.y*stats[25]+stats[28];
        float i2 = v.z*stats[26]+stats[29];
        a0 = i0*lin_r_w[c0] + i1*lin_r_w[HC+c0] + i2*lin_r_w[2*HC+c0];
        a1 = i0*lin_r_w[c0+1] + i1*lin_r_w[HC+c0+1] + i2*lin_r_w[2*HC+c0+1];
    }
    a0 = leaky(a0); a1 = leaky(a1);
    *(float2*)(x + (size_t)node*HC + c0) = make_float2(a0, a1);
    unsigned pk = (unsigned)f2bf(a0) | ((unsigned)f2bf(a1) << 16);
    *(unsigned*)(xb + (size_t)node*HC + c0) = pk;
}

// ---------------- degree / CSR build ----------------
__global__ void count_kernel(const int* __restrict__ dst, int* __restrict__ cnt){
    int base = blockIdx.x*1024 + threadIdx.x;
    int d0 = dst[base];
    int d1 = dst[base + 256];
    int d2 = dst[base + 512];
    int d3 = dst[base + 768];
    atomicAdd(&cnt[d0], 1);
    atomicAdd(&cnt[d1], 1);
    atomicAdd(&cnt[d2], 1);
    atomicAdd(&cnt[d3], 1);
}

__global__ void scan_block_kernel(const int* __restrict__ cnt, int* __restrict__ rp,
                                  int* __restrict__ bsum){
    __shared__ int sh[1024];
    int tid = threadIdx.x;
    int i = blockIdx.x*1024 + tid;
    int v = cnt[i];
    sh[tid] = v;
    __syncthreads();
    for (int off=1; off<1024; off<<=1){
        int t = (tid >= off) ? sh[tid-off] : 0;
        __syncthreads();
        sh[tid] += t;
        __syncthreads();
    }
    rp[i] = sh[tid] - v;                 // exclusive within block
    if (tid == 1023) bsum[blockIdx.x] = sh[1023];
}

__global__ void scan_sums_kernel(int* __restrict__ bsum, int* __restrict__ rp){
    int run = 0;
    for (int b=0;b<SCAN_NB;b++){ int t = bsum[b]; bsum[b] = run; run += t; }
    rp[NN] = run;
}

__global__ void offsets_kernel(int* __restrict__ rp, const int* __restrict__ bsum,
        const int* __restrict__ cnt, int* __restrict__ cursor, float* __restrict__ dinv){
    int i = blockIdx.x*256 + threadIdx.x;   // grid = NN/256 exact
    int r = rp[i] + bsum[i >> 10];
    rp[i] = r; cursor[i] = r;
    dinv[i] = rsqrtf((float)(cnt[i] + 1));  // +1 self loop
}

__global__ void scatter_kernel(const int* __restrict__ src, const int* __restrict__ dst,
        const float* __restrict__ dinv, int* __restrict__ cursor, int2* __restrict__ csr){
    int base = blockIdx.x*1024 + threadIdx.x;
    int s0 = src[base],       d0 = dst[base];
    int s1 = src[base + 256], d1 = dst[base + 256];
    int s2 = src[base + 512], d2 = dst[base + 512];
    int s3 = src[base + 768], d3 = dst[base + 768];
    float w0 = dinv[s0]*dinv[d0];
    float w1 = dinv[s1]*dinv[d1];
    float w2 = dinv[s2]*dinv[d2];
    float w3 = dinv[s3]*dinv[d3];
    int p0 = atomicAdd(&cursor[d0], 1);
    int p1 = atomicAdd(&cursor[d1], 1);
    int p2 = atomicAdd(&cursor[d2], 1);
    int p3 = atomicAdd(&cursor[d3], 1);
    csr[p0] = make_int2(s0, __float_as_int(w0));
    csr[p1] = make_int2(s1, __float_as_int(w1));
    csr[p2] = make_int2(s2, __float_as_int(w2));
    csr[p3] = make_int2(s3, __float_as_int(w3));
}

// ---------------- W pre-swizzle: fp32 [k][n] -> bf16 B-fragment layout ----------------
// slot = (nt*4+ks)*64 + lane ; per slot 8 bf16 = B[ks*32 + (lane>>4)*8 + j][nt*16 + (lane&15)]
__global__ void wswz_kernel(const float* __restrict__ conv_w, uint4* __restrict__ wswz){
    int l = blockIdx.x;
    const float* Wg = conv_w + (size_t)l*HC*HC;
    int tid = threadIdx.x;
    #pragma unroll
    for (int i=0;i<8;i++){
        int slot = tid + i*256;       // 0..2047
        int g = slot >> 6;            // nt*4+ks
        int ln = slot & 63;
        int nt = g >> 2, ks = g & 3;
        int q = ln >> 4, n = nt*16 + (ln & 15);
        int k0 = ks*32 + q*8;
        unsigned short h[8];
        #pragma unroll
        for (int j=0;j<8;j++) h[j] = f2bf(Wg[(size_t)(k0+j)*HC + n]);
        uint4 o;
        o.x = (unsigned)h[0] | ((unsigned)h[1]<<16);
        o.y = (unsigned)h[2] | ((unsigned)h[3]<<16);
        o.z = (unsigned)h[4] | ((unsigned)h[5]<<16);
        o.w = (unsigned)h[6] | ((unsigned)h[7]<<16);
        wswz[(size_t)l*2048 + slot] = o;
    }
}

// ---------------- conv GEMM: xw(bf16) = xb(bf16) @ W (MFMA 16x16x32) ----------------
// block: 256 thr = 4 waves, 64 rows x 128 cols per block
__global__ __launch_bounds__(256) void gemm_kernel(const unsigned short* __restrict__ xb,
        const uint4* __restrict__ wswz, unsigned short* __restrict__ xw){
    __shared__ uint4 Wlds[2048];              // 32 KB, B-frag layout
    __shared__ unsigned short outb[64*136];   // 17 KB, pitch 136 (16B-aligned rows)
    int tid = threadIdx.x;
    #pragma unroll
    for (int i=0;i<8;i++){
        int slot = tid + i*256;
        Wlds[slot] = wswz[slot];
    }
    int lane = tid & 63, w = tid >> 6;
    int q = lane >> 4, m = lane & 15;
    int row = blockIdx.x*64 + w*16 + m;
    const v8s* arow = (const v8s*)(xb + (size_t)row*HC + q*8);
    v4f acc[8];
    #pragma unroll
    for (int nt=0;nt<8;nt++) acc[nt] = (v4f){0.f,0.f,0.f,0.f};
    __syncthreads();
    #pragma unroll
    for (int ks=0; ks<4; ks++){
        v8s a = arow[ks*4];                   // ks*32 elems = ks*4 v8s
        #pragma unroll
        for (int nt=0;nt<8;nt++){
            v8s b = *(const v8s*)&Wlds[(nt*4+ks)*64 + lane];
            acc[nt] = __builtin_amdgcn_mfma_f32_16x16x32_bf16(a, b, acc[nt], 0, 0, 0);
        }
    }
    // C/D layout: col = lane&15 (= m), row(tile) = q*4 + reg
    #pragma unroll
    for (int nt=0;nt<8;nt++){
        #pragma unroll
        for (int i=0;i<4;i++){
            outb[(w*16 + q*4 + i)*136 + nt*16 + m] = f2bf(acc[nt][i]);
        }
    }
    __syncthreads();
    size_t gbase = (size_t)blockIdx.x * 64 * HC;
    #pragma unroll
    for (int i=0;i<4;i++){
        int c = tid + i*256;                  // 1024 chunks of 16B
        int r = c >> 4, j = c & 15;
        uint4 v = *(const uint4*)&outb[r*136 + j*8];
        *(uint4*)&xw[gbase + (size_t)r*HC + j*8] = v;
    }
}

// ---------------- aggregation: x += leaky(A_norm @ xw + b), xw bf16, unroll 4 ----------------
__global__ __launch_bounds__(256) void agg_kernel(const unsigned short* __restrict__ xw,
        const int* __restrict__ rp, const int2* __restrict__ csr,
        const float* __restrict__ dinv, const float* __restrict__ bias,
        float* __restrict__ x, unsigned short* __restrict__ xb){
    int lane = threadIdx.x & 63;
    int node = blockIdx.x*4 + (threadIdx.x >> 6);
    int half = lane >> 5;           // edge parity for this lane
    int c4 = (lane & 31) * 4;       // channel quad
    int beg = rp[node], end = rp[node+1];

    float4 acc0 = make_float4(0.f,0.f,0.f,0.f);
    float4 acc1 = make_float4(0.f,0.f,0.f,0.f);
    float4 acc2 = make_float4(0.f,0.f,0.f,0.f);
    float4 acc3 = make_float4(0.f,0.f,0.f,0.f);

    int j = beg + half;
    while (j + 6 < end){
        int2 e0 = csr[j];
        int2 e1 = csr[j+2];
        int2 e2 = csr[j+4];
        int2 e3 = csr[j+6];
        float4 v0 = bf4_to_f4(*(const uint2*)(xw + (size_t)e0.x*HC + c4));
        float4 v1 = bf4_to_f4(*(const uint2*)(xw + (size_t)e1.x*HC + c4));
        float4 v2 = bf4_to_f4(*(const uint2*)(xw + (size_t)e2.x*HC + c4));
        float4 v3 = bf4_to_f4(*(const uint2*)(xw + (size_t)e3.x*HC + c4));
        float w0 = __int_as_float(e0.y);
        float w1 = __int_as_float(e1.y);
        float w2 = __int_as_float(e2.y);
        float w3 = __int_as_float(e3.y);
        acc0.x += w0*v0.x; acc0.y += w0*v0.y; acc0.z += w0*v0.z; acc0.w += w0*v0.w;
        acc1.x += w1*v1.x; acc1.y += w1*v1.y; acc1.z += w1*v1.z; acc1.w += w1*v1.w;
        acc2.x += w2*v2.x; acc2.y += w2*v2.y; acc2.z += w2*v2.z; acc2.w += w2*v2.w;
        acc3.x += w3*v3.x; acc3.y += w3*v3.y; acc3.z += w3*v3.z; acc3.w += w3*v3.w;
        j += 8;
    }
    while (j < end){
        int2 e = csr[j];
        float4 v = bf4_to_f4(*(const uint2*)(xw + (size_t)e.x*HC + c4));
        float w = __int_as_float(e.y);
        acc0.x += w*v.x; acc0.y += w*v.y; acc0.z += w*v.z; acc0.w += w*v.w;
        j += 2;
    }
    acc0.x += acc1.x + acc2.x + acc3.x;
    acc0.y += acc1.y + acc2.y + acc3.y;
    acc0.z += acc1.z + acc2.z + acc3.z;
    acc0.w += acc1.w + acc2.w + acc3.w;
    // self loop (half0 only)
    if (half == 0){
        float dn = dinv[node];
        float4 sv = bf4_to_f4(*(const uint2*)(xw + (size_t)node*HC + c4));
        float sw = dn*dn;
        acc0.x += sw*sv.x; acc0.y += sw*sv.y; acc0.z += sw*sv.z; acc0.w += sw*sv.w;
    }
    // cross-half combine: lanes 0..31 += lanes 32..63
    acc0.x += __shfl_down(acc0.x, 32, 64);
    acc0.y += __shfl_down(acc0.y, 32, 64);
    acc0.z += __shfl_down(acc0.z, 32, 64);
    acc0.w += __shfl_down(acc0.w, 32, 64);
    if (half == 0){
        float4 b4 = *(const float4*)(bias + c4);
        size_t idx = (size_t)node*HC + c4;
        float4 xv = *(const float4*)(x + idx);
        xv.x += leaky(acc0.x + b4.x);
        xv.y += leaky(acc0.y + b4.y);
        xv.z += leaky(acc0.z + b4.z);
        xv.w += leaky(acc0.w + b4.w);
        *(float4*)(x + idx) = xv;
        uint2 pk;
        pk.x = (unsigned)f2bf(xv.x) | ((unsigned)f2bf(xv.y) << 16);
        pk.y = (unsigned)f2bf(xv.z) | ((unsigned)f2bf(xv.w) << 16);
        *(uint2*)(xb + idx) = pk;
    }
}

// ---------------- channel-mean pool ----------------
__global__ void pool_kernel(const float* __restrict__ x, float* __restrict__ pooled){
    int wid = threadIdx.x >> 6;
    int lane = threadIdx.x & 63;
    int node = blockIdx.x*4 + wid;
    const float* row = x + (size_t)node*HC;
    float v = row[lane] + row[64 + lane];
    #pragma unroll
    for (int off=32; off>0; off>>=1) v += __shfl_down(v, off, 64);
    if (lane == 0) pooled[node] = v * (1.f/128.f);
}

// ---------------- heads: z, o, output ----------------
__global__ void head_kernel(const float* __restrict__ pooled, const float* __restrict__ r_x,
        const float* __restrict__ linr_w, const float* __restrict__ linr_b,
        const float* __restrict__ lino_w1, const float* __restrict__ lino_b1,
        const float* __restrict__ lino_w2, const float* __restrict__ lino_b2,
        float* __restrict__ out){
    int b = blockIdx.x, tid = threadIdx.x;
    __shared__ float red[128][8];
    __shared__ float hsh[128];
    __shared__ float zsh[8];
    float part[NO];
    #pragma unroll
    for (int j=0;j<NO;j++) part[j]=0.f;
    for (int i = tid; i < SR; i += 128){
        float pv = pooled[(size_t)b*SR + i];
        #pragma unroll
        for (int j=0;j<NO;j++) part[j] += pv * linr_w[i*NO + j];
    }
    #pragma unroll
    for (int j=0;j<NO;j++) red[tid][j] = part[j];
    // o path: h[c]
    const float* ox = r_x + (size_t)b*RDIM*8 + RC;
    float hv = lino_b1[tid];
    #pragma unroll
    for (int k=0;k<5;k++) hv += ox[k]*lino_w1[k*HC + tid];
    hsh[tid] = leaky(hv);
    __syncthreads();
    for (int s=64; s>0; s>>=1){
        if (tid < s){
            #pragma unroll
            for (int j=0;j<NO;j++) red[tid][j] += red[tid+s][j];
        }
        __syncthreads();
    }
    if (tid < NO) zsh[tid] = expf(red[0][tid] + linr_b[tid]);
    __syncthreads();
    if (tid < NO){
        float zsum = 0.f;
        #pragma unroll
        for (int j=0;j<NO;j++) zsum += zsh[j];
        float z = zsh[tid] / (zsum + 1.f);
        float o = lino_b2[tid];
        for (int cc=0; cc<HC; cc++) o += hsh[cc]*lino_w2[cc*NO + tid];
        out[b*NO + tid] = z * expf(o);
    }
}

extern "C" void kernel_launch(void* const* d_in, const int* in_sizes, int n_in,
                              void* d_out, int out_size, void* d_ws, size_t ws_size,
                              hipStream_t stream) {
    const float* s_x     = (const float*)d_in[0];
    const float* r_x     = (const float*)d_in[1];
    const int*   ei      = (const int*)d_in[2];
    const float* bn_s_w  = (const float*)d_in[3];
    const float* bn_s_b  = (const float*)d_in[4];
    const float* bn_r_w  = (const float*)d_in[5];
    const float* bn_r_b  = (const float*)d_in[6];
    const float* lin_s_w = (const float*)d_in[7];
    const float* lin_r_w = (const float*)d_in[8];
    const float* conv_w  = (const float*)d_in[9];
    const float* conv_b  = (const float*)d_in[10];
    const float* linr_w  = (const float*)d_in[11];
    const float* linr_b  = (const float*)d_in[12];
    const float* lino_w1 = (const float*)d_in[13];
    const float* lino_b1 = (const float*)d_in[14];
    const float* lino_w2 = (const float*)d_in[15];
    const float* lino_b2 = (const float*)d_in[16];
    float* out = (float*)d_out;

    char* ws = (char*)d_ws;
    size_t off = 0;
    auto alloc = [&](size_t bytes)->void*{
        void* p = ws + off;
        off = (off + bytes + 255) & ~(size_t)255;
        return p;
    };
    float* x        = (float*)alloc((size_t)NN*HC*4);
    unsigned short* xb = (unsigned short*)alloc((size_t)NN*HC*2);
    unsigned short* xw = (unsigned short*)alloc((size_t)NN*HC*2);
    int*   cnt      = (int*)  alloc((size_t)NN*4);
    float* dinv     = (float*)alloc((size_t)NN*4);
    int*   rp       = (int*)  alloc((size_t)(NN+1)*4);
    int*   cursor   = (int*)  alloc((size_t)NN*4);
    int2*  csr      = (int2*) alloc((size_t)EE*8);
    float* stats    = (float*)alloc(64*4);
    int*   bsum     = (int*)  alloc(256*4);
    float* pooled   = (float*)alloc((size_t)NN*4);
    uint4* wswz     = (uint4*)alloc((size_t)LCONV*2048*16);

    hipMemsetAsync(cnt, 0, (size_t)NN*4, stream);
    hipMemsetAsync(stats, 0, 64*4, stream);

    stats_s_kernel<<<(NS+255)/256, 256, 0, stream>>>(s_x, stats);
    stats_r_kernel<<<(NR+255)/256, 256, 0, stream>>>(r_x, stats);
    finalize_stats_kernel<<<1, 64, 0, stream>>>(stats, bn_s_w, bn_s_b, bn_r_w, bn_r_b);
    feature_kernel<<<NN/4, 256, 0, stream>>>(s_x, r_x, stats, lin_s_w, lin_r_w, x, xb);
    wswz_kernel<<<LCONV, 256, 0, stream>>>(conv_w, wswz);

    count_kernel<<<EE/1024, 256, 0, stream>>>(ei + EE, cnt);
    scan_block_kernel<<<SCAN_NB, 1024, 0, stream>>>(cnt, rp, bsum);
    scan_sums_kernel<<<1, 1, 0, stream>>>(bsum, rp);
    offsets_kernel<<<NN/256, 256, 0, stream>>>(rp, bsum, cnt, cursor, dinv);
    scatter_kernel<<<EE/1024, 256, 0, stream>>>(ei, ei + EE, dinv, cursor, csr);

    for (int l = 0; l < LCONV; l++){
        gemm_kernel<<<NN/64, 256, 0, stream>>>(xb, wswz + (size_t)l*2048, xw);
        agg_kernel<<<NN/4, 256, 0, stream>>>(xw, rp, csr, dinv, conv_b + (size_t)l*HC, x, xb);
    }

    pool_kernel<<<NN/4, 256, 0, stream>>>(x, pooled);
    head_kernel<<<BATCH, 128, 0, stream>>>(pooled, r_x, linr_w, linr_b,
                                           lino_w1, lino_b1, lino_w2, lino_b2, out);
}